// Round 5
// baseline (554.157 us; speedup 1.0000x reference)
//
#include <hip/hip_runtime.h>
#include <hip/hip_cooperative_groups.h>

namespace cg = cooperative_groups;

// InstanceRouteOptimizationArea — RUDY map via impulse/cumsum trick.
// Round 5: single cooperative kernel. R2-R4 cross-round arithmetic showed
// ~35-40us of total time not attributable to in-kernel work -> inter-kernel
// drain/flush boundaries. Fuse all phases with grid.sync(); interleave
// pin_pos into float2 first to halve the random gathers.

#define NB 256
#define NW 8          // rows per accumulation window
#define NWIN 32       // NB/NW
#define MAXCHUNK 32

__device__ __forceinline__ long long load_idx(const void* p, long long i, int is64) {
    if (is64) return ((const long long*)p)[i];
    return (long long)((const int*)p)[i];
}

// ======================= fused cooperative kernel =======================
__global__ __launch_bounds__(256) void fused_kernel(
        const float* __restrict__ pos,
        const float* __restrict__ pin_pos,
        const float* __restrict__ nsx,
        const float* __restrict__ nsy,
        const float* __restrict__ net_weights,
        const void* __restrict__ netpin_start,
        const void* __restrict__ flat_netpin,
        float2* __restrict__ pp2,
        unsigned* __restrict__ wmask,
        float2* __restrict__ yb,
        float4* __restrict__ rd,
        float* __restrict__ P,
        float* __restrict__ G,
        float* __restrict__ utilT,
        float* __restrict__ out,
        int num_nets, int num_pins, int num_nodes, int num_movable, int nchunk)
{
    cg::grid_group grid = cg::this_grid();
    __shared__ float smem[2 * NW * NB];   // 16 KiB, reused per phase
    const int tid = threadIdx.x;
    const int bid = blockIdx.x;
    const int nthr = gridDim.x * blockDim.x;
    const int gtid = bid * blockDim.x + tid;
    const float BSX = 3.90625f;
    const float INVB = 1.0f / 3.90625f;
    const int is64 = (((const int*)netpin_start)[1] == 0);

    // ---- P0: interleave pin coords (one 8B gather later instead of two 4B)
    for (int p = gtid; p < num_pins; p += nthr)
        pp2[p] = make_float2(pin_pos[p], pin_pos[p + num_pins]);
    grid.sync();

    // ---- P1: per-net bbox (4 lanes/net) + densities + window mask
    for (int item = gtid; item < 4 * num_nets; item += nthr) {
        int n = item >> 2, k = item & 3;
        long long s = load_idx(netpin_start, n, is64);
        long long e = load_idx(netpin_start, n + 1, is64);
        float xmn = 3e38f, xmx = -3e38f, ymn = 3e38f, ymx = -3e38f;
        if (e - s == 4) {
            long long pin = load_idx(flat_netpin, s + k, is64);
            float2 p = pp2[pin];
            xmn = p.x; xmx = p.x; ymn = p.y; ymx = p.y;
        } else if (k == 0) {
            for (long long q = s; q < e; ++q) {
                long long pin = load_idx(flat_netpin, q, is64);
                float2 p = pp2[pin];
                xmn = fminf(xmn, p.x); xmx = fmaxf(xmx, p.x);
                ymn = fminf(ymn, p.y); ymx = fmaxf(ymx, p.y);
            }
        }
        #pragma unroll
        for (int m = 1; m <= 2; m <<= 1) {
            xmn = fminf(xmn, __shfl_xor(xmn, m));
            xmx = fmaxf(xmx, __shfl_xor(xmx, m));
            ymn = fminf(ymn, __shfl_xor(ymn, m));
            ymx = fmaxf(ymx, __shfl_xor(ymx, m));
        }
        if (k == 0) {
            if (e <= s) {
                wmask[n] = 0u;
                yb[n] = make_float2(0.f, 0.f);
                rd[n] = make_float4(0.f, 0.f, 0.f, 0.f);
            } else {
                float wx = xmx - xmn, wy = ymx - ymn;
                float area = fmaxf(wx * wy, 1e-6f);
                float w = net_weights[n];
                int j0 = (int)floorf(ymn * INVB);
                int j1 = (int)floorf(ymx * INVB);
                unsigned m = 0u;
                if ((unsigned)j0 < 256u)       m |= 1u << (j0 >> 3);
                if ((unsigned)(j0 + 1) < 256u) m |= 1u << ((j0 + 1) >> 3);
                if ((unsigned)j1 < 256u)       m |= 1u << (j1 >> 3);
                if ((unsigned)(j1 + 1) < 256u) m |= 1u << ((j1 + 1) >> 3);
                wmask[n] = m;
                yb[n] = make_float2(ymn, ymx);
                rd[n] = make_float4(xmn, xmx, w * wx / area, w * wy / area);
            }
        }
    }
    grid.sync();

    // ---- P2: LDS-tile impulse accumulation -> partial grids P
    if (bid < NWIN * nchunk) {
        const int win = bid & (NWIN - 1);
        const int chunk = bid >> 5;          // NWIN==32
        const int r0 = win * NW;
        for (int i = tid; i < 2 * NW * NB; i += blockDim.x) smem[i] = 0.f;
        __syncthreads();
        const int c0 = (int)((long long)num_nets * chunk / nchunk);
        const int c1 = (int)((long long)num_nets * (chunk + 1) / nchunk);
        for (int n = c0 + tid; n < c1; n += blockDim.x) {
            if (!((wmask[n] >> win) & 1u)) continue;
            float2 y = yb[n];
            float4 r = rd[n];
            float ty0 = y.x * INVB, fj0 = floorf(ty0); int j0 = (int)fj0; float f0 = ty0 - fj0;
            float ty1 = y.y * INVB, fj1 = floorf(ty1); int j1 = (int)fj1; float f1 = ty1 - fj1;
            float tx0 = r.x * INVB, g0 = floorf(tx0); int i0 = (int)g0; float h0 = tx0 - g0;
            float tx1 = r.y * INVB, g1 = floorf(tx1); int i1 = (int)g1; float h1 = tx1 - g1;
            int   jxs[4] = { i0, i0 + 1, i1, i1 + 1 };
            float axs[4] = { BSX * (1.f - h0), BSX * h0, -BSX * (1.f - h1), -BSX * h1 };
            int   rr[4]  = { j0, j0 + 1, j1, j1 + 1 };
            float rw[4]  = { BSX * (1.f - f0), BSX * f0, -BSX * (1.f - f1), -BSX * f1 };
            #pragma unroll
            for (int q = 0; q < 4; ++q) {
                int row = rr[q] - r0;
                if ((unsigned)row >= NW) continue;
                float wh = rw[q] * r.z;
                float wv = rw[q] * r.w;
                float* bh = smem + row * NB;
                float* bv = smem + NW * NB + row * NB;
                #pragma unroll
                for (int p = 0; p < 4; ++p) {
                    int x = jxs[p];
                    if (x >= NB) continue;
                    atomicAdd(bh + x, axs[p] * wh);
                    atomicAdd(bv + x, axs[p] * wv);
                }
            }
        }
        __syncthreads();
        for (int i = tid; i < 2 * NW * NB; i += blockDim.x) {
            int p = i / (NW * NB);
            int rr2 = (i / NB) % NW;
            int x = i & (NB - 1);
            P[(((long long)chunk * 2 + p) * NB + r0 + rr2) * NB + x] = smem[i];
        }
    }
    grid.sync();

    // ---- P3: reduce partials + row cumsum -> G (h plane, v plane)
    for (int y = bid; y < NB; y += gridDim.x) {
        float h = 0.f, v = 0.f;
        for (int c = 0; c < nchunk; ++c) {
            h += P[(((long long)c * 2 + 0) * NB + y) * NB + tid];
            v += P[(((long long)c * 2 + 1) * NB + y) * NB + tid];
        }
        float* sh = smem;
        float* sv = smem + NB;
        sh[tid] = h; sv[tid] = v;
        #pragma unroll
        for (int off = 1; off < NB; off <<= 1) {
            __syncthreads();
            float a = (tid >= off) ? sh[tid - off] : 0.0f;
            float b = (tid >= off) ? sv[tid - off] : 0.0f;
            __syncthreads();
            sh[tid] += a; sv[tid] += b;
        }
        __syncthreads();
        G[y * NB + tid] = sh[tid];
        G[NB * NB + y * NB + tid] = sv[tid];
        __syncthreads();
    }
    grid.sync();

    // ---- P4: column cumsum + util (transposed store [x][y])
    for (int x = bid; x < NB; x += gridDim.x) {
        const float INV_CH = 1.0f / (3.90625f * 3.90625f * 1.5625f);
        const float INV_CV = 1.0f / (3.90625f * 3.90625f * 1.45f);
        float* sh = smem;
        float* sv = smem + NB;
        sh[tid] = G[tid * NB + x];
        sv[tid] = G[NB * NB + tid * NB + x];
        #pragma unroll
        for (int off = 1; off < NB; off <<= 1) {
            __syncthreads();
            float a = (tid >= off) ? sh[tid - off] : 0.0f;
            float b = (tid >= off) ? sv[tid - off] : 0.0f;
            __syncthreads();
            sh[tid] += a; sv[tid] += b;
        }
        __syncthreads();
        float u = fmaxf(sh[tid] * INV_CH, sv[tid] * INV_CV);
        u = fminf(fmaxf(u, 0.5f), 2.0f);
        utilT[x * NB + tid] = u;
        __syncthreads();
    }
    grid.sync();

    // ---- P5: per-instance area (util transposed [x][y])
    for (int i = gtid; i < num_movable; i += nthr) {
        float x0f = pos[i];
        float y0f = pos[num_nodes + i];
        float x1f = x0f + nsx[i];
        float y1f = y0f + nsy[i];
        int kx0 = max(0, min(NB - 1, (int)floorf(x0f * INVB)));
        int kx1 = max(0, min(NB - 1, (int)floorf(x1f * INVB)));
        int ky0 = max(0, min(NB - 1, (int)floorf(y0f * INVB)));
        int ky1 = max(0, min(NB - 1, (int)floorf(y1f * INVB)));
        float acc = 0.0f;
        for (int kx = kx0; kx <= kx1; ++kx) {
            float bx = kx * BSX;
            float ovx = fmaxf(fminf(x1f, bx + BSX) - fmaxf(x0f, bx), 0.0f);
            const float* ucol = utilT + kx * NB;
            float accy = 0.0f;
            for (int ky = ky0; ky <= ky1; ++ky) {
                float by = ky * BSX;
                float ovy = fmaxf(fminf(y1f, by + BSX) - fmaxf(y0f, by), 0.0f);
                accy += ovy * ucol[ky];
            }
            acc += accy * ovx;
        }
        out[i] = acc;
    }
}

// ======================= fallback multi-kernel path =======================
__global__ void bbox_kernel(const float* __restrict__ pin_pos,
                            const float* __restrict__ net_weights,
                            const void* __restrict__ netpin_start,
                            const void* __restrict__ flat_netpin,
                            unsigned* __restrict__ wmask,
                            float2* __restrict__ yb,
                            float4* __restrict__ rd,
                            int num_nets, int num_pins) {
    int gid = blockIdx.x * blockDim.x + threadIdx.x;
    int n = gid >> 2, k = gid & 3;
    if (n >= num_nets) return;
    const int is64 = (((const int*)netpin_start)[1] == 0);
    long long s = load_idx(netpin_start, n, is64);
    long long e = load_idx(netpin_start, n + 1, is64);
    float xmn = 3e38f, xmx = -3e38f, ymn = 3e38f, ymx = -3e38f;
    if (e - s == 4) {
        long long pin = load_idx(flat_netpin, s + k, is64);
        float px = pin_pos[pin], py = pin_pos[pin + num_pins];
        xmn = px; xmx = px; ymn = py; ymx = py;
    } else if (k == 0) {
        for (long long p = s; p < e; ++p) {
            long long pin = load_idx(flat_netpin, p, is64);
            float px = pin_pos[pin], py = pin_pos[pin + num_pins];
            xmn = fminf(xmn, px); xmx = fmaxf(xmx, px);
            ymn = fminf(ymn, py); ymx = fmaxf(ymx, py);
        }
    }
    #pragma unroll
    for (int m = 1; m <= 2; m <<= 1) {
        xmn = fminf(xmn, __shfl_xor(xmn, m));
        xmx = fmaxf(xmx, __shfl_xor(xmx, m));
        ymn = fminf(ymn, __shfl_xor(ymn, m));
        ymx = fmaxf(ymx, __shfl_xor(ymx, m));
    }
    if (k) return;
    if (e <= s) {
        wmask[n] = 0u;
        yb[n] = make_float2(0.f, 0.f);
        rd[n] = make_float4(0.f, 0.f, 0.f, 0.f);
        return;
    }
    float wx = xmx - xmn, wy = ymx - ymn;
    float area = fmaxf(wx * wy, 1e-6f);
    float w = net_weights[n];
    const float INVB = 1.0f / 3.90625f;
    int j0 = (int)floorf(ymn * INVB);
    int j1 = (int)floorf(ymx * INVB);
    unsigned m = 0u;
    if ((unsigned)j0 < 256u)       m |= 1u << (j0 >> 3);
    if ((unsigned)(j0 + 1) < 256u) m |= 1u << ((j0 + 1) >> 3);
    if ((unsigned)j1 < 256u)       m |= 1u << (j1 >> 3);
    if ((unsigned)(j1 + 1) < 256u) m |= 1u << ((j1 + 1) >> 3);
    wmask[n] = m;
    yb[n] = make_float2(ymn, ymx);
    rd[n] = make_float4(xmn, xmx, w * wx / area, w * wy / area);
}

__global__ __launch_bounds__(512) void accum_kernel(
        const unsigned* __restrict__ wmask,
        const float2* __restrict__ yb,
        const float4* __restrict__ rd,
        float* __restrict__ P,
        int num_nets, int nchunk) {
    __shared__ float acc[2 * NW * NB];
    const int win = blockIdx.x & (NWIN - 1);
    const int chunk = blockIdx.x >> 5;
    const int r0 = win * NW;
    const int tid = threadIdx.x;
    const int bs = blockDim.x;
    for (int i = tid; i < 2 * NW * NB; i += bs) acc[i] = 0.f;
    __syncthreads();
    const int c0 = (int)((long long)num_nets * chunk / nchunk);
    const int c1 = (int)((long long)num_nets * (chunk + 1) / nchunk);
    const float BSX = 3.90625f;
    const float INVB = 1.0f / 3.90625f;
    for (int n = c0 + tid; n < c1; n += bs) {
        if (!((wmask[n] >> win) & 1u)) continue;
        float2 y = yb[n];
        float4 r = rd[n];
        float ty0 = y.x * INVB, fj0 = floorf(ty0); int j0 = (int)fj0; float f0 = ty0 - fj0;
        float ty1 = y.y * INVB, fj1 = floorf(ty1); int j1 = (int)fj1; float f1 = ty1 - fj1;
        float tx0 = r.x * INVB, g0 = floorf(tx0); int i0 = (int)g0; float h0 = tx0 - g0;
        float tx1 = r.y * INVB, g1 = floorf(tx1); int i1 = (int)g1; float h1 = tx1 - g1;
        int   jxs[4] = { i0, i0 + 1, i1, i1 + 1 };
        float axs[4] = { BSX * (1.f - h0), BSX * h0, -BSX * (1.f - h1), -BSX * h1 };
        int   rr[4]  = { j0, j0 + 1, j1, j1 + 1 };
        float rw[4]  = { BSX * (1.f - f0), BSX * f0, -BSX * (1.f - f1), -BSX * f1 };
        #pragma unroll
        for (int q = 0; q < 4; ++q) {
            int row = rr[q] - r0;
            if ((unsigned)row >= NW) continue;
            float wh = rw[q] * r.z;
            float wv = rw[q] * r.w;
            float* bh = acc + row * NB;
            float* bv = acc + NW * NB + row * NB;
            #pragma unroll
            for (int p = 0; p < 4; ++p) {
                int x = jxs[p];
                if (x >= NB) continue;
                atomicAdd(bh + x, axs[p] * wh);
                atomicAdd(bv + x, axs[p] * wv);
            }
        }
    }
    __syncthreads();
    for (int i = tid; i < 2 * NW * NB; i += bs) {
        int p = i / (NW * NB);
        int r = (i / NB) % NW;
        int x = i & (NB - 1);
        P[(((long long)chunk * 2 + p) * NB + r0 + r) * NB + x] = acc[i];
    }
}

__global__ void reduce_scan(const float* __restrict__ P, float* __restrict__ G,
                            int nchunk) {
    int y = blockIdx.x, t = threadIdx.x;
    float h = 0.f, v = 0.f;
    for (int c = 0; c < nchunk; ++c) {
        h += P[(((long long)c * 2 + 0) * NB + y) * NB + t];
        v += P[(((long long)c * 2 + 1) * NB + y) * NB + t];
    }
    __shared__ float sh[NB];
    __shared__ float sv[NB];
    sh[t] = h; sv[t] = v;
    #pragma unroll
    for (int off = 1; off < NB; off <<= 1) {
        __syncthreads();
        float a = (t >= off) ? sh[t - off] : 0.0f;
        float b = (t >= off) ? sv[t - off] : 0.0f;
        __syncthreads();
        sh[t] += a; sv[t] += b;
    }
    __syncthreads();
    G[y * NB + t] = sh[t];
    G[NB * NB + y * NB + t] = sv[t];
}

__global__ void col_scan_util(const float* __restrict__ G, float* __restrict__ utilT) {
    int x = blockIdx.x, t = threadIdx.x;
    const float INV_CH = 1.0f / (3.90625f * 3.90625f * 1.5625f);
    const float INV_CV = 1.0f / (3.90625f * 3.90625f * 1.45f);
    __shared__ float sh[NB];
    __shared__ float sv[NB];
    sh[t] = G[t * NB + x];
    sv[t] = G[NB * NB + t * NB + x];
    #pragma unroll
    for (int off = 1; off < NB; off <<= 1) {
        __syncthreads();
        float a = (t >= off) ? sh[t - off] : 0.0f;
        float b = (t >= off) ? sv[t - off] : 0.0f;
        __syncthreads();
        sh[t] += a; sv[t] += b;
    }
    __syncthreads();
    float u = fmaxf(sh[t] * INV_CH, sv[t] * INV_CV);
    u = fminf(fmaxf(u, 0.5f), 2.0f);
    utilT[x * NB + t] = u;
}

__global__ void instance_area(const float* __restrict__ pos,
                              const float* __restrict__ nsx,
                              const float* __restrict__ nsy,
                              const float* __restrict__ utilT,
                              float* __restrict__ out,
                              int num_movable, int num_nodes) {
    int i = blockIdx.x * blockDim.x + threadIdx.x;
    if (i >= num_movable) return;
    const float BSX = 3.90625f;
    const float INVB = 1.0f / 3.90625f;
    float x0f = pos[i];
    float y0f = pos[num_nodes + i];
    float x1f = x0f + nsx[i];
    float y1f = y0f + nsy[i];
    int kx0 = max(0, min(NB - 1, (int)floorf(x0f * INVB)));
    int kx1 = max(0, min(NB - 1, (int)floorf(x1f * INVB)));
    int ky0 = max(0, min(NB - 1, (int)floorf(y0f * INVB)));
    int ky1 = max(0, min(NB - 1, (int)floorf(y1f * INVB)));
    float acc = 0.0f;
    for (int kx = kx0; kx <= kx1; ++kx) {
        float bx = kx * BSX;
        float ovx = fmaxf(fminf(x1f, bx + BSX) - fmaxf(x0f, bx), 0.0f);
        const float* ucol = utilT + kx * NB;
        float accy = 0.0f;
        for (int ky = ky0; ky <= ky1; ++ky) {
            float by = ky * BSX;
            float ovy = fmaxf(fminf(y1f, by + BSX) - fmaxf(y0f, by), 0.0f);
            accy += ovy * ucol[ky];
        }
        acc += accy * ovx;
    }
    out[i] = acc;
}

extern "C" void kernel_launch(void* const* d_in, const int* in_sizes, int n_in,
                              void* d_out, int out_size, void* d_ws, size_t ws_size,
                              hipStream_t stream) {
    const float* pos          = (const float*)d_in[0];
    const float* pin_pos      = (const float*)d_in[1];
    const float* nsx          = (const float*)d_in[2];
    const float* nsy          = (const float*)d_in[3];
    const float* net_weights  = (const float*)d_in[4];
    const void*  netpin_start = d_in[5];
    const void*  flat_netpin  = d_in[6];
    float* out = (float*)d_out;

    int num_pins    = in_sizes[1] / 2;
    int num_nodes   = in_sizes[2];
    int num_nets    = in_sizes[4];
    int num_movable = out_size;

    // Workspace (floats): pp2[2*pins] | wmask[n] | yb[2n] | rd[4n] |
    //                     P[nchunk*2*65536] | G[2*65536] | utilT[65536]
    size_t pp_f   = 2LL * num_pins;
    size_t mk_f   = (size_t)num_nets;
    size_t yb_f   = 2LL * num_nets;
    size_t rd_f   = 4LL * num_nets;
    size_t grid_f = (size_t)NB * NB * 2;
    size_t util_f = (size_t)NB * NB;
    size_t fixed  = pp_f + mk_f + yb_f + rd_f + grid_f + util_f;
    long long avail = (long long)(ws_size / sizeof(float)) - (long long)fixed;
    int max_nchunk = (int)(avail / (long long)grid_f);
    if (max_nchunk > MAXCHUNK) max_nchunk = MAXCHUNK;

    float2*   pp2 = (float2*)d_ws;
    unsigned* wmask = (unsigned*)((float*)d_ws + pp_f);
    float2*   yb  = (float2*)((float*)d_ws + pp_f + mk_f);
    float4*   rd  = (float4*)((float*)d_ws + pp_f + mk_f + yb_f);
    float*    P   = (float*)d_ws + pp_f + mk_f + yb_f + rd_f;

    // Decide cooperative path (host-only queries; capture-safe).
    int dev = 0; hipGetDevice(&dev);
    int coop = 0;
    hipDeviceGetAttribute(&coop, hipDeviceAttributeCooperativeLaunch, dev);
    int numCU = 0;
    hipDeviceGetAttribute(&numCU, hipDeviceAttributeMultiprocessorCount, dev);
    int blocksPerCU = 0;
    hipOccupancyMaxActiveBlocksPerMultiprocessor(&blocksPerCU,
        reinterpret_cast<const void*>(fused_kernel), 256, 0);

    int nchunk = max_nchunk;
    int gridBlocks = 0;
    if (coop && blocksPerCU > 0 && nchunk >= 1) {
        int cap = blocksPerCU * numCU;
        if (nchunk * NWIN > cap) nchunk = cap / NWIN;
        if (nchunk > 0) gridBlocks = nchunk * NWIN;
    }

    if (gridBlocks >= NWIN) {
        float* G  = P + (size_t)nchunk * grid_f;
        float* ut = G + grid_f;
        void* args[] = {
            (void*)&pos, (void*)&pin_pos, (void*)&nsx, (void*)&nsy,
            (void*)&net_weights, (void*)&netpin_start, (void*)&flat_netpin,
            (void*)&pp2, (void*)&wmask, (void*)&yb, (void*)&rd,
            (void*)&P, (void*)&G, (void*)&ut, (void*)&out,
            (void*)&num_nets, (void*)&num_pins, (void*)&num_nodes,
            (void*)&num_movable, (void*)&nchunk };
        hipError_t err = hipLaunchCooperativeKernel(
            reinterpret_cast<const void*>(fused_kernel),
            dim3(gridBlocks), dim3(256), args, 0, stream);
        if (err == hipSuccess) return;
        // fall through to multi-kernel path on failure
    }

    // -------- fallback: round-4 multi-kernel path --------
    {
        int nch = max_nchunk < 1 ? 1 : max_nchunk;
        float* G  = P + (size_t)nch * grid_f;
        float* ut = G + grid_f;
        int g1 = (4 * num_nets + 255) / 256;
        bbox_kernel<<<g1, 256, 0, stream>>>(pin_pos, net_weights, netpin_start,
                                            flat_netpin, wmask, yb, rd,
                                            num_nets, num_pins);
        accum_kernel<<<NWIN * nch, 512, 0, stream>>>(wmask, yb, rd, P,
                                                     num_nets, nch);
        reduce_scan<<<NB, 256, 0, stream>>>(P, G, nch);
        col_scan_util<<<NB, 256, 0, stream>>>(G, ut);
        int gi = (num_movable + 255) / 256;
        instance_area<<<gi, 256, 0, stream>>>(pos, nsx, nsy, ut, out,
                                              num_movable, num_nodes);
    }
}

// Round 6
// 123.098 us; speedup vs baseline: 4.5018x; 4.5018x over previous
//
#include <hip/hip_runtime.h>

// InstanceRouteOptimizationArea — RUDY map via impulse/cumsum trick.
// Round 6: fused single kernel with HAND-ROLLED grid barrier.
// R5 showed cg::grid.sync() costs ~80us/sync on MI355X (554us total, all idle).
// Here: 256 blocks (== CU count -> co-resident), barrier = atomicAdd(agent) +
// relaxed spin + one __threadfence() on exit. Counters zeroed per launch by a
// 16B hipMemsetAsync graph node. nchunk=8 -> 4MB partials.
// Phases: P0 bbox -> P1 LDS-tile accum -> P2 chunk-reduce+row-scan ->
//         P3 col-scan+util(transposed) -> P4 instance areas.

#define NB 256
#define NBLK 256       // grid size == CU count (co-residency)
#define THREADS 512
#define NW 8           // rows per accumulation window
#define NWIN 32        // NB/NW
#define NCHUNK 8       // NWIN*NCHUNK == NBLK

__device__ __forceinline__ long long load_idx(const void* p, long long i, int is64) {
    if (is64) return ((const long long*)p)[i];
    return (long long)((const int*)p)[i];
}

__device__ __forceinline__ void grid_barrier(unsigned* cnt) {
    __syncthreads();   // all waves drain their memory ops (compiler emits vmcnt(0))
    if (threadIdx.x == 0) {
        __hip_atomic_fetch_add(cnt, 1u, __ATOMIC_RELEASE, __HIP_MEMORY_SCOPE_AGENT);
        long long guard = 0;
        while (__hip_atomic_load(cnt, __ATOMIC_RELAXED, __HIP_MEMORY_SCOPE_AGENT)
               < (unsigned)NBLK) {
            __builtin_amdgcn_s_sleep(2);
            if (++guard > (100LL << 20)) break;   // safety valve: fail clean, not hang
        }
        __threadfence();   // acquire side: invalidate caches once after rendezvous
    }
    __syncthreads();
}

__global__ __launch_bounds__(THREADS) void fused1(
        const float* __restrict__ pos,
        const float* __restrict__ pin_pos,
        const float* __restrict__ nsx,
        const float* __restrict__ nsy,
        const float* __restrict__ net_weights,
        const void* __restrict__ netpin_start,
        const void* __restrict__ flat_netpin,
        unsigned* __restrict__ cnt,      // 4 barrier counters (memset to 0)
        unsigned* __restrict__ wmask,
        float2* __restrict__ yb,
        float4* __restrict__ rd,
        float* __restrict__ P,           // [NCHUNK][2][NB][NB]
        float* __restrict__ G,           // [2][NB][NB]
        float* __restrict__ utilT,       // [NB(x)][NB(y)]
        float* __restrict__ out,
        int num_nets, int num_pins, int num_nodes, int num_movable)
{
    __shared__ float smem[2 * NW * NB];   // 16 KiB (accum tile; scans reuse front)
    const int tid = threadIdx.x;
    const int bid = blockIdx.x;
    const int gtid = bid * THREADS + tid;
    const int nthr = NBLK * THREADS;
    const float BSX = 3.90625f;
    const float INVB = 1.0f / 3.90625f;
    const int is64 = (((const int*)netpin_start)[1] == 0);

    // ---------------- P0: per-net bbox + densities + window mask ----------
    for (int n = gtid; n < num_nets; n += nthr) {
        long long s = load_idx(netpin_start, n, is64);
        long long e = load_idx(netpin_start, n + 1, is64);
        if (e <= s) { wmask[n] = 0u; continue; }
        float xmn = 3e38f, xmx = -3e38f, ymn = 3e38f, ymx = -3e38f;
        if (e - s == 4) {
            long long p0 = load_idx(flat_netpin, s, is64);
            long long p1 = load_idx(flat_netpin, s + 1, is64);
            long long p2 = load_idx(flat_netpin, s + 2, is64);
            long long p3 = load_idx(flat_netpin, s + 3, is64);
            float x0 = pin_pos[p0], x1 = pin_pos[p1], x2 = pin_pos[p2], x3 = pin_pos[p3];
            float y0 = pin_pos[p0 + num_pins], y1 = pin_pos[p1 + num_pins];
            float y2 = pin_pos[p2 + num_pins], y3 = pin_pos[p3 + num_pins];
            xmn = fminf(fminf(x0, x1), fminf(x2, x3));
            xmx = fmaxf(fmaxf(x0, x1), fmaxf(x2, x3));
            ymn = fminf(fminf(y0, y1), fminf(y2, y3));
            ymx = fmaxf(fmaxf(y0, y1), fmaxf(y2, y3));
        } else {
            for (long long q = s; q < e; ++q) {
                long long pin = load_idx(flat_netpin, q, is64);
                float px = pin_pos[pin], py = pin_pos[pin + num_pins];
                xmn = fminf(xmn, px); xmx = fmaxf(xmx, px);
                ymn = fminf(ymn, py); ymx = fmaxf(ymx, py);
            }
        }
        float wx = xmx - xmn, wy = ymx - ymn;
        float area = fmaxf(wx * wy, 1e-6f);
        float w = net_weights[n];
        int j0 = (int)floorf(ymn * INVB);
        int j1 = (int)floorf(ymx * INVB);
        unsigned m = 0u;
        if ((unsigned)j0 < 256u)       m |= 1u << (j0 >> 3);
        if ((unsigned)(j0 + 1) < 256u) m |= 1u << ((j0 + 1) >> 3);
        if ((unsigned)j1 < 256u)       m |= 1u << (j1 >> 3);
        if ((unsigned)(j1 + 1) < 256u) m |= 1u << ((j1 + 1) >> 3);
        wmask[n] = m;
        yb[n] = make_float2(ymn, ymx);
        rd[n] = make_float4(xmn, xmx, w * wx / area, w * wy / area);
    }
    grid_barrier(cnt + 0);

    // ---------------- P1: LDS-tile impulse accumulation -> P ----------------
    {
        const int win = bid & (NWIN - 1);
        const int chunk = bid >> 5;          // NWIN==32
        const int r0 = win * NW;
        for (int i = tid; i < 2 * NW * NB; i += THREADS) smem[i] = 0.f;
        __syncthreads();
        const int c0 = (int)((long long)num_nets * chunk / NCHUNK);
        const int c1 = (int)((long long)num_nets * (chunk + 1) / NCHUNK);
        for (int n = c0 + tid; n < c1; n += THREADS) {
            if (!((wmask[n] >> win) & 1u)) continue;
            float2 y = yb[n];
            float4 r = rd[n];
            float ty0 = y.x * INVB, fj0 = floorf(ty0); int j0 = (int)fj0; float f0 = ty0 - fj0;
            float ty1 = y.y * INVB, fj1 = floorf(ty1); int j1 = (int)fj1; float f1 = ty1 - fj1;
            float tx0 = r.x * INVB, g0 = floorf(tx0); int i0 = (int)g0; float h0 = tx0 - g0;
            float tx1 = r.y * INVB, g1 = floorf(tx1); int i1 = (int)g1; float h1 = tx1 - g1;
            int   jxs[4] = { i0, i0 + 1, i1, i1 + 1 };
            float axs[4] = { BSX * (1.f - h0), BSX * h0, -BSX * (1.f - h1), -BSX * h1 };
            int   rr[4]  = { j0, j0 + 1, j1, j1 + 1 };
            float rw[4]  = { BSX * (1.f - f0), BSX * f0, -BSX * (1.f - f1), -BSX * f1 };
            #pragma unroll
            for (int q = 0; q < 4; ++q) {
                int row = rr[q] - r0;
                if ((unsigned)row >= NW) continue;
                float wh = rw[q] * r.z;
                float wv = rw[q] * r.w;
                float* bh = smem + row * NB;
                float* bv = smem + NW * NB + row * NB;
                #pragma unroll
                for (int p = 0; p < 4; ++p) {
                    int x = jxs[p];
                    if (x >= NB) continue;
                    atomicAdd(bh + x, axs[p] * wh);
                    atomicAdd(bv + x, axs[p] * wv);
                }
            }
        }
        __syncthreads();
        for (int i = tid; i < 2 * NW * NB; i += THREADS) {
            int p = i / (NW * NB);
            int rr2 = (i / NB) % NW;
            int x = i & (NB - 1);
            P[(((long long)chunk * 2 + p) * NB + r0 + rr2) * NB + x] = smem[i];
        }
    }
    grid_barrier(cnt + 1);

    // ---------------- P2: chunk-reduce + row cumsum -> G -------------------
    {
        const int y = bid;                 // one row per block
        const int plane = tid >> 8;        // 0: h, 1: v
        const int tt = tid & (NB - 1);     // x
        float s = 0.f;
        #pragma unroll
        for (int c = 0; c < NCHUNK; ++c)
            s += P[(((long long)c * 2 + plane) * NB + y) * NB + tt];
        float* buf = smem;                 // [2][NB]
        buf[plane * NB + tt] = s;
        #pragma unroll
        for (int off = 1; off < NB; off <<= 1) {
            __syncthreads();
            float a = (tt >= off) ? buf[plane * NB + tt - off] : 0.0f;
            __syncthreads();
            buf[plane * NB + tt] += a;
        }
        __syncthreads();
        G[(long long)plane * NB * NB + y * NB + tt] = buf[plane * NB + tt];
    }
    grid_barrier(cnt + 2);

    // ---------------- P3: column cumsum + util (transposed [x][y]) ---------
    {
        const int x = bid;                 // one column per block
        const int plane = tid >> 8;
        const int tt = tid & (NB - 1);     // y
        float* buf = smem;
        buf[plane * NB + tt] = G[(long long)plane * NB * NB + tt * NB + x];
        #pragma unroll
        for (int off = 1; off < NB; off <<= 1) {
            __syncthreads();
            float a = (tt >= off) ? buf[plane * NB + tt - off] : 0.0f;
            __syncthreads();
            buf[plane * NB + tt] += a;
        }
        __syncthreads();
        if (plane == 0) {
            const float INV_CH = 1.0f / (3.90625f * 3.90625f * 1.5625f);
            const float INV_CV = 1.0f / (3.90625f * 3.90625f * 1.45f);
            float u = fmaxf(buf[tt] * INV_CH, buf[NB + tt] * INV_CV);
            u = fminf(fmaxf(u, 0.5f), 2.0f);
            utilT[x * NB + tt] = u;
        }
    }
    grid_barrier(cnt + 3);

    // ---------------- P4: per-instance area --------------------------------
    for (int i = gtid; i < num_movable; i += nthr) {
        float x0f = pos[i];
        float y0f = pos[num_nodes + i];
        float x1f = x0f + nsx[i];
        float y1f = y0f + nsy[i];
        int kx0 = max(0, min(NB - 1, (int)floorf(x0f * INVB)));
        int kx1 = max(0, min(NB - 1, (int)floorf(x1f * INVB)));
        int ky0 = max(0, min(NB - 1, (int)floorf(y0f * INVB)));
        int ky1 = max(0, min(NB - 1, (int)floorf(y1f * INVB)));
        float acc = 0.0f;
        for (int kx = kx0; kx <= kx1; ++kx) {
            float bx = kx * BSX;
            float ovx = fmaxf(fminf(x1f, bx + BSX) - fmaxf(x0f, bx), 0.0f);
            const float* ucol = utilT + kx * NB;
            float accy = 0.0f;
            for (int ky = ky0; ky <= ky1; ++ky) {
                float by = ky * BSX;
                float ovy = fmaxf(fminf(y1f, by + BSX) - fmaxf(y0f, by), 0.0f);
                accy += ovy * ucol[ky];
            }
            acc += accy * ovx;
        }
        out[i] = acc;
    }
}

// ======================= minimal fallback (tiny workspace) ==================
__global__ void fb_zero(float* g, int n) {
    int i = blockIdx.x * blockDim.x + threadIdx.x;
    int stride = gridDim.x * blockDim.x;
    for (; i < n; i += stride) g[i] = 0.0f;
}

__global__ void fb_scatter(const float* __restrict__ pin_pos,
                           const float* __restrict__ net_weights,
                           const void* __restrict__ netpin_start,
                           const void* __restrict__ flat_netpin,
                           float* __restrict__ G2,
                           int num_nets, int num_pins) {
    int n = blockIdx.x * blockDim.x + threadIdx.x;
    if (n >= num_nets) return;
    const int is64 = (((const int*)netpin_start)[1] == 0);
    long long s = load_idx(netpin_start, n, is64);
    long long e = load_idx(netpin_start, n + 1, is64);
    if (e <= s) return;
    float xmn = 3e38f, xmx = -3e38f, ymn = 3e38f, ymx = -3e38f;
    for (long long p = s; p < e; ++p) {
        long long pin = load_idx(flat_netpin, p, is64);
        float px = pin_pos[pin], py = pin_pos[pin + num_pins];
        xmn = fminf(xmn, px); xmx = fmaxf(xmx, px);
        ymn = fminf(ymn, py); ymx = fmaxf(ymx, py);
    }
    float wx = xmx - xmn, wy = ymx - ymn;
    float area = fmaxf(wx * wy, 1e-6f);
    float w = net_weights[n];
    float dh = w * wx / area, dv = w * wy / area;
    const float BSX = 3.90625f, INVB = 1.0f / 3.90625f;
    int jx[4]; float ax[4]; int jy[4]; float ay[4];
    float t, fj, f; int j;
    t = xmn * INVB; fj = floorf(t); j = (int)fj; f = t - fj;
    jx[0] = j; ax[0] = BSX * (1.f - f); jx[1] = j + 1; ax[1] = BSX * f;
    t = xmx * INVB; fj = floorf(t); j = (int)fj; f = t - fj;
    jx[2] = j; ax[2] = -BSX * (1.f - f); jx[3] = j + 1; ax[3] = -BSX * f;
    t = ymn * INVB; fj = floorf(t); j = (int)fj; f = t - fj;
    jy[0] = j; ay[0] = BSX * (1.f - f); jy[1] = j + 1; ay[1] = BSX * f;
    t = ymx * INVB; fj = floorf(t); j = (int)fj; f = t - fj;
    jy[2] = j; ay[2] = -BSX * (1.f - f); jy[3] = j + 1; ay[3] = -BSX * f;
    #pragma unroll
    for (int b = 0; b < 4; ++b) {
        int y = jy[b];
        if (y < 0 || y >= NB) continue;
        #pragma unroll
        for (int a2 = 0; a2 < 4; ++a2) {
            int x = jx[a2];
            if (x < 0 || x >= NB) continue;
            float g = ax[a2] * ay[b];
            atomicAdd(&G2[(y * NB + x) * 2],     dh * g);
            atomicAdd(&G2[(y * NB + x) * 2 + 1], dv * g);
        }
    }
}

__global__ void fb_rowscan(float2* G2) {
    int y = blockIdx.x, t = threadIdx.x;
    __shared__ float sh[NB]; __shared__ float sv[NB];
    float2 v = G2[y * NB + t];
    sh[t] = v.x; sv[t] = v.y;
    #pragma unroll
    for (int off = 1; off < NB; off <<= 1) {
        __syncthreads();
        float a = (t >= off) ? sh[t - off] : 0.0f;
        float b = (t >= off) ? sv[t - off] : 0.0f;
        __syncthreads();
        sh[t] += a; sv[t] += b;
    }
    __syncthreads();
    G2[y * NB + t] = make_float2(sh[t], sv[t]);
}

__global__ void fb_colscan(const float2* __restrict__ G2, float* __restrict__ util) {
    int x = threadIdx.x;
    const float INV_CH = 1.0f / (3.90625f * 3.90625f * 1.5625f);
    const float INV_CV = 1.0f / (3.90625f * 3.90625f * 1.45f);
    float rh = 0.f, rv = 0.f;
    for (int y = 0; y < NB; ++y) {
        float2 g = G2[y * NB + x];
        rh += g.x; rv += g.y;
        float u = fmaxf(rh * INV_CH, rv * INV_CV);
        util[y * NB + x] = fminf(fmaxf(u, 0.5f), 2.0f);
    }
}

__global__ void fb_instance(const float* __restrict__ pos,
                            const float* __restrict__ nsx,
                            const float* __restrict__ nsy,
                            const float* __restrict__ util,
                            float* __restrict__ out,
                            int num_movable, int num_nodes) {
    int i = blockIdx.x * blockDim.x + threadIdx.x;
    if (i >= num_movable) return;
    const float BSX = 3.90625f, INVB = 1.0f / 3.90625f;
    float x0f = pos[i], y0f = pos[num_nodes + i];
    float x1f = x0f + nsx[i], y1f = y0f + nsy[i];
    int kx0 = max(0, min(NB - 1, (int)floorf(x0f * INVB)));
    int kx1 = max(0, min(NB - 1, (int)floorf(x1f * INVB)));
    int ky0 = max(0, min(NB - 1, (int)floorf(y0f * INVB)));
    int ky1 = max(0, min(NB - 1, (int)floorf(y1f * INVB)));
    float acc = 0.0f;
    for (int ky = ky0; ky <= ky1; ++ky) {
        float by = ky * BSX;
        float ovy = fmaxf(fminf(y1f, by + BSX) - fmaxf(y0f, by), 0.0f);
        const float* urow = util + ky * NB;
        float accx = 0.0f;
        for (int kx = kx0; kx <= kx1; ++kx) {
            float bx = kx * BSX;
            float ovx = fmaxf(fminf(x1f, bx + BSX) - fmaxf(x0f, bx), 0.0f);
            accx += ovx * urow[kx];
        }
        acc += accx * ovy;
    }
    out[i] = acc;
}

extern "C" void kernel_launch(void* const* d_in, const int* in_sizes, int n_in,
                              void* d_out, int out_size, void* d_ws, size_t ws_size,
                              hipStream_t stream) {
    const float* pos          = (const float*)d_in[0];
    const float* pin_pos      = (const float*)d_in[1];
    const float* nsx          = (const float*)d_in[2];
    const float* nsy          = (const float*)d_in[3];
    const float* net_weights  = (const float*)d_in[4];
    const void*  netpin_start = d_in[5];
    const void*  flat_netpin  = d_in[6];
    float* out = (float*)d_out;

    int num_pins    = in_sizes[1] / 2;
    int num_nodes   = in_sizes[2];
    int num_nets    = in_sizes[4];
    int num_movable = out_size;

    // Workspace layout (float units, 16B-aligned sections):
    // cnt[4](u32) | wmask[n] | yb[2n] | rd[4n] | P[NCHUNK*2*NB*NB] | G[2*NB*NB] | utilT[NB*NB]
    auto align4 = [](size_t v) { return (v + 3) & ~(size_t)3; };
    size_t cnt_off  = 0;
    size_t mk_off   = 4;
    size_t yb_off   = align4(mk_off + (size_t)num_nets);
    size_t rd_off   = align4(yb_off + 2LL * num_nets);
    size_t P_off    = align4(rd_off + 4LL * num_nets);
    size_t grid_f   = (size_t)NB * NB * 2;
    size_t G_off    = P_off + (size_t)NCHUNK * grid_f;
    size_t ut_off   = G_off + grid_f;
    size_t need     = (ut_off + (size_t)NB * NB) * sizeof(float);

    if (ws_size >= need) {
        float* base = (float*)d_ws;
        unsigned* cnt   = (unsigned*)(base + cnt_off);
        unsigned* wmask = (unsigned*)(base + mk_off);
        float2*   yb    = (float2*)(base + yb_off);
        float4*   rd    = (float4*)(base + rd_off);
        float*    P     = base + P_off;
        float*    G     = base + G_off;
        float*    ut    = base + ut_off;

        hipMemsetAsync(cnt, 0, 4 * sizeof(unsigned), stream);
        fused1<<<NBLK, THREADS, 0, stream>>>(
            pos, pin_pos, nsx, nsy, net_weights, netpin_start, flat_netpin,
            cnt, wmask, yb, rd, P, G, ut, out,
            num_nets, num_pins, num_nodes, num_movable);
        return;
    }

    // -------- fallback: round-1 style (768KB workspace) --------
    {
        float* G2   = (float*)d_ws;
        float* util = G2 + NB * NB * 2;
        fb_zero<<<256, 256, 0, stream>>>(G2, NB * NB * 2);
        int gn = (num_nets + 255) / 256;
        fb_scatter<<<gn, 256, 0, stream>>>(pin_pos, net_weights, netpin_start,
                                           flat_netpin, G2, num_nets, num_pins);
        fb_rowscan<<<NB, 256, 0, stream>>>((float2*)G2);
        fb_colscan<<<1, 256, 0, stream>>>((const float2*)G2, util);
        int gi = (num_movable + 255) / 256;
        fb_instance<<<gi, 256, 0, stream>>>(pos, nsx, nsy, util, out,
                                            num_movable, num_nodes);
    }
}

// Round 7
// 81.770 us; speedup vs baseline: 6.7770x; 1.5054x over previous
//
#include <hip/hip_runtime.h>

// InstanceRouteOptimizationArea — RUDY map via impulse/cumsum trick.
// Round 7: 3 kernels, 2 boundaries. Lessons: in-kernel grid barriers cost
// ~20us each on 8 XCDs (R5/R6) -> use kernel boundaries; latency-chain
// phases need few iterations/thread + many waves/SIMD (R2's 48us accum was
// 49 serialized iters at 1 wave/SIMD).
//  K1 accum_fused: bbox gather (x8 window replication, L2-resident) +
//     LDS impulse splat + in-tile x-cumsum + coalesced float4 store.
//     grid 256 (NWIN=8 x NCHUNK=32), 1024 thr -> 3 iters/thread.
//  K2 colscan_util: sum 32 chunk tiles + y-cumsum + clip -> utilT[x][y].
//  K3 instance_area: <=3x3 bin dot product per instance.

#define NB 256
#define NW 32          // rows per accumulation window
#define NWIN 8         // NB/NW
#define NCHUNK 32      // net chunks; grid = NWIN*NCHUNK = 256
#define K1_THREADS 1024
#define NWAVES (K1_THREADS / 64)

__device__ __forceinline__ long long load_idx(const void* p, long long i, int is64) {
    if (is64) return ((const long long*)p)[i];
    return (long long)((const int*)p)[i];
}

// ---------------- K1: gather + windowed splat + x-cumsum ----------------
__global__ __launch_bounds__(K1_THREADS) void accum_fused(
        const float* __restrict__ pin_pos,
        const float* __restrict__ net_weights,
        const void* __restrict__ netpin_start,
        const void* __restrict__ flat_netpin,
        float* __restrict__ P,          // [NCHUNK][2][NB][NB]
        int num_nets, int num_pins) {
    __shared__ float acc[2 * NW * NB];  // [plane][row][x], 64 KiB
    const int win   = blockIdx.x & (NWIN - 1);
    const int chunk = blockIdx.x >> 3;      // NWIN == 8
    const int r0    = win * NW;
    const int tid   = threadIdx.x;
    const int is64  = (((const int*)netpin_start)[1] == 0);
    const float BSX  = 3.90625f;
    const float INVB = 1.0f / 3.90625f;

    for (int i = tid; i < 2 * NW * NB; i += K1_THREADS) acc[i] = 0.f;
    __syncthreads();

    const int c0 = (int)((long long)num_nets * chunk / NCHUNK);
    const int c1 = (int)((long long)num_nets * (chunk + 1) / NCHUNK);
    for (int n = c0 + tid; n < c1; n += K1_THREADS) {
        long long s = load_idx(netpin_start, n, is64);
        long long e = load_idx(netpin_start, n + 1, is64);
        if (e <= s) continue;
        float xmn, xmx, ymn, ymx;
        if (e - s == 4) {
            long long q0 = load_idx(flat_netpin, s,     is64);
            long long q1 = load_idx(flat_netpin, s + 1, is64);
            long long q2 = load_idx(flat_netpin, s + 2, is64);
            long long q3 = load_idx(flat_netpin, s + 3, is64);
            float x0 = pin_pos[q0], x1 = pin_pos[q1];
            float x2 = pin_pos[q2], x3 = pin_pos[q3];
            float y0 = pin_pos[q0 + num_pins], y1 = pin_pos[q1 + num_pins];
            float y2 = pin_pos[q2 + num_pins], y3 = pin_pos[q3 + num_pins];
            xmn = fminf(fminf(x0, x1), fminf(x2, x3));
            xmx = fmaxf(fmaxf(x0, x1), fmaxf(x2, x3));
            ymn = fminf(fminf(y0, y1), fminf(y2, y3));
            ymx = fmaxf(fmaxf(y0, y1), fmaxf(y2, y3));
        } else {
            xmn = 3e38f; xmx = -3e38f; ymn = 3e38f; ymx = -3e38f;
            for (long long q = s; q < e; ++q) {
                long long pin = load_idx(flat_netpin, q, is64);
                float px = pin_pos[pin], py = pin_pos[pin + num_pins];
                xmn = fminf(xmn, px); xmx = fmaxf(xmx, px);
                ymn = fminf(ymn, py); ymx = fmaxf(ymx, py);
            }
        }
        float ty0 = ymn * INVB, fj0 = floorf(ty0);
        float ty1 = ymx * INVB, fj1 = floorf(ty1);
        int j0 = (int)fj0, j1 = (int)fj1;
        // rows {j0, j0+1, j1, j1+1} vs window [r0, r0+NW)
        bool hit = ((unsigned)(j0 + 1 - r0) <= NW) || ((unsigned)(j1 + 1 - r0) <= NW);
        if (!hit) continue;
        float f0 = ty0 - fj0, f1 = ty1 - fj1;
        float wx = xmx - xmn, wy = ymx - ymn;
        float area = fmaxf(wx * wy, 1e-6f);
        float w = net_weights[n];
        float dh = w * wx / area;
        float dv = w * wy / area;
        float tx0 = xmn * INVB, g0 = floorf(tx0);
        float tx1 = xmx * INVB, g1 = floorf(tx1);
        int i0 = (int)g0, i1 = (int)g1;
        float h0 = tx0 - g0, h1 = tx1 - g1;
        int   jxs[4] = { i0, i0 + 1, i1, i1 + 1 };
        float axs[4] = { BSX * (1.f - h0), BSX * h0, -BSX * (1.f - h1), -BSX * h1 };
        int   rr[4]  = { j0, j0 + 1, j1, j1 + 1 };
        float rw[4]  = { BSX * (1.f - f0), BSX * f0, -BSX * (1.f - f1), -BSX * f1 };
        #pragma unroll
        for (int q = 0; q < 4; ++q) {
            int row = rr[q] - r0;
            if ((unsigned)row >= NW) continue;
            float wh = rw[q] * dh;
            float wv = rw[q] * dv;
            float* bh = acc + row * NB;
            float* bv = acc + NW * NB + row * NB;
            #pragma unroll
            for (int p = 0; p < 4; ++p) {
                int x = jxs[p];
                if (x >= NB) continue;
                atomicAdd(bh + x, axs[p] * wh);
                atomicAdd(bv + x, axs[p] * wv);
            }
        }
    }
    __syncthreads();

    // In-tile x-cumsum: 64 rows (2 planes x 32), one wave per row, shfl scan.
    const int wave = tid >> 6, lane = tid & 63;
    for (int row = wave; row < 2 * NW; row += NWAVES) {
        float* base = acc + row * NB;
        float carry = 0.f;
        #pragma unroll
        for (int seg = 0; seg < NB / 64; ++seg) {
            float v = base[seg * 64 + lane];
            #pragma unroll
            for (int off = 1; off < 64; off <<= 1) {
                float u = __shfl_up(v, off);
                if (lane >= off) v += u;
            }
            v += carry;
            base[seg * 64 + lane] = v;
            carry = __shfl(v, 63);
        }
    }
    __syncthreads();

    // Coalesced float4 store: P[chunk][plane][r0+row][x]
    const float4* a4 = (const float4*)acc;
    float4* P4 = (float4*)P;
    for (int i = tid; i < 2 * NW * (NB / 4); i += K1_THREADS) {
        int p   = i / (NW * 64);
        int rem = i - p * (NW * 64);
        int row = rem / 64;
        int x4  = rem % 64;
        P4[(((long long)chunk * 2 + p) * NB + (r0 + row)) * 64 + x4] = a4[i];
    }
}

// ---------------- K2: chunk-sum + y-cumsum + util (transposed) ----------
__global__ __launch_bounds__(512) void colscan_util(
        const float* __restrict__ P, float* __restrict__ utilT) {
    __shared__ float buf[2 * NB];
    const int x = blockIdx.x;
    const int plane = threadIdx.x >> 8;   // 0: h, 1: v
    const int y = threadIdx.x & (NB - 1);
    float s = 0.f;
    #pragma unroll 8
    for (int c = 0; c < NCHUNK; ++c)
        s += P[(((long long)c * 2 + plane) * NB + y) * NB + x];
    float* b = buf + plane * NB;
    b[y] = s;
    #pragma unroll
    for (int off = 1; off < NB; off <<= 1) {
        __syncthreads();
        float a = (y >= off) ? b[y - off] : 0.0f;
        __syncthreads();
        b[y] += a;
    }
    __syncthreads();
    if (plane == 0) {
        const float INV_CH = 1.0f / (3.90625f * 3.90625f * 1.5625f);
        const float INV_CV = 1.0f / (3.90625f * 3.90625f * 1.45f);
        float u = fmaxf(buf[y] * INV_CH, buf[NB + y] * INV_CV);
        u = fminf(fmaxf(u, 0.5f), 2.0f);
        utilT[x * NB + y] = u;   // [x][y], coalesced
    }
}

// ---------------- K3: per-instance area (util transposed [x][y]) --------
__global__ void instance_area(const float* __restrict__ pos,
                              const float* __restrict__ nsx,
                              const float* __restrict__ nsy,
                              const float* __restrict__ utilT,
                              float* __restrict__ out,
                              int num_movable, int num_nodes) {
    int i = blockIdx.x * blockDim.x + threadIdx.x;
    if (i >= num_movable) return;
    const float BSX = 3.90625f;
    const float INVB = 1.0f / 3.90625f;
    float x0f = pos[i];
    float y0f = pos[num_nodes + i];
    float x1f = x0f + nsx[i];
    float y1f = y0f + nsy[i];
    int kx0 = max(0, min(NB - 1, (int)floorf(x0f * INVB)));
    int kx1 = max(0, min(NB - 1, (int)floorf(x1f * INVB)));
    int ky0 = max(0, min(NB - 1, (int)floorf(y0f * INVB)));
    int ky1 = max(0, min(NB - 1, (int)floorf(y1f * INVB)));
    float acc = 0.0f;
    for (int kx = kx0; kx <= kx1; ++kx) {
        float bx = kx * BSX;
        float ovx = fmaxf(fminf(x1f, bx + BSX) - fmaxf(x0f, bx), 0.0f);
        const float* ucol = utilT + kx * NB;
        float accy = 0.0f;
        for (int ky = ky0; ky <= ky1; ++ky) {
            float by = ky * BSX;
            float ovy = fmaxf(fminf(y1f, by + BSX) - fmaxf(y0f, by), 0.0f);
            accy += ovy * ucol[ky];
        }
        acc += accy * ovx;
    }
    out[i] = acc;
}

// ---------------- fallback (tiny workspace): round-1 style ----------------
__global__ void fb_zero(float* g, int n) {
    int i = blockIdx.x * blockDim.x + threadIdx.x;
    int stride = gridDim.x * blockDim.x;
    for (; i < n; i += stride) g[i] = 0.0f;
}

__global__ void fb_scatter(const float* __restrict__ pin_pos,
                           const float* __restrict__ net_weights,
                           const void* __restrict__ netpin_start,
                           const void* __restrict__ flat_netpin,
                           float* __restrict__ G2,
                           int num_nets, int num_pins) {
    int n = blockIdx.x * blockDim.x + threadIdx.x;
    if (n >= num_nets) return;
    const int is64 = (((const int*)netpin_start)[1] == 0);
    long long s = load_idx(netpin_start, n, is64);
    long long e = load_idx(netpin_start, n + 1, is64);
    if (e <= s) return;
    float xmn = 3e38f, xmx = -3e38f, ymn = 3e38f, ymx = -3e38f;
    for (long long p = s; p < e; ++p) {
        long long pin = load_idx(flat_netpin, p, is64);
        float px = pin_pos[pin], py = pin_pos[pin + num_pins];
        xmn = fminf(xmn, px); xmx = fmaxf(xmx, px);
        ymn = fminf(ymn, py); ymx = fmaxf(ymx, py);
    }
    float wx = xmx - xmn, wy = ymx - ymn;
    float area = fmaxf(wx * wy, 1e-6f);
    float w = net_weights[n];
    float dh = w * wx / area, dv = w * wy / area;
    const float BSX = 3.90625f, INVB = 1.0f / 3.90625f;
    int jx[4]; float ax[4]; int jy[4]; float ay[4];
    float t, fj, f; int j;
    t = xmn * INVB; fj = floorf(t); j = (int)fj; f = t - fj;
    jx[0] = j; ax[0] = BSX * (1.f - f); jx[1] = j + 1; ax[1] = BSX * f;
    t = xmx * INVB; fj = floorf(t); j = (int)fj; f = t - fj;
    jx[2] = j; ax[2] = -BSX * (1.f - f); jx[3] = j + 1; ax[3] = -BSX * f;
    t = ymn * INVB; fj = floorf(t); j = (int)fj; f = t - fj;
    jy[0] = j; ay[0] = BSX * (1.f - f); jy[1] = j + 1; ay[1] = BSX * f;
    t = ymx * INVB; fj = floorf(t); j = (int)fj; f = t - fj;
    jy[2] = j; ay[2] = -BSX * (1.f - f); jy[3] = j + 1; ay[3] = -BSX * f;
    #pragma unroll
    for (int b = 0; b < 4; ++b) {
        int y = jy[b];
        if (y < 0 || y >= NB) continue;
        #pragma unroll
        for (int a2 = 0; a2 < 4; ++a2) {
            int x = jx[a2];
            if (x < 0 || x >= NB) continue;
            float g = ax[a2] * ay[b];
            atomicAdd(&G2[(y * NB + x) * 2],     dh * g);
            atomicAdd(&G2[(y * NB + x) * 2 + 1], dv * g);
        }
    }
}

__global__ void fb_rowscan(float2* G2) {
    int y = blockIdx.x, t = threadIdx.x;
    __shared__ float sh[NB]; __shared__ float sv[NB];
    float2 v = G2[y * NB + t];
    sh[t] = v.x; sv[t] = v.y;
    #pragma unroll
    for (int off = 1; off < NB; off <<= 1) {
        __syncthreads();
        float a = (t >= off) ? sh[t - off] : 0.0f;
        float b = (t >= off) ? sv[t - off] : 0.0f;
        __syncthreads();
        sh[t] += a; sv[t] += b;
    }
    __syncthreads();
    G2[y * NB + t] = make_float2(sh[t], sv[t]);
}

__global__ void fb_colscan(const float2* __restrict__ G2, float* __restrict__ utilT) {
    int x = blockIdx.x, t = threadIdx.x;
    const float INV_CH = 1.0f / (3.90625f * 3.90625f * 1.5625f);
    const float INV_CV = 1.0f / (3.90625f * 3.90625f * 1.45f);
    __shared__ float sh[NB]; __shared__ float sv[NB];
    float2 g = G2[t * NB + x];
    sh[t] = g.x; sv[t] = g.y;
    #pragma unroll
    for (int off = 1; off < NB; off <<= 1) {
        __syncthreads();
        float a = (t >= off) ? sh[t - off] : 0.0f;
        float b = (t >= off) ? sv[t - off] : 0.0f;
        __syncthreads();
        sh[t] += a; sv[t] += b;
    }
    __syncthreads();
    float u = fmaxf(sh[t] * INV_CH, sv[t] * INV_CV);
    utilT[x * NB + t] = fminf(fmaxf(u, 0.5f), 2.0f);
}

extern "C" void kernel_launch(void* const* d_in, const int* in_sizes, int n_in,
                              void* d_out, int out_size, void* d_ws, size_t ws_size,
                              hipStream_t stream) {
    const float* pos          = (const float*)d_in[0];
    const float* pin_pos      = (const float*)d_in[1];
    const float* nsx          = (const float*)d_in[2];
    const float* nsy          = (const float*)d_in[3];
    const float* net_weights  = (const float*)d_in[4];
    const void*  netpin_start = d_in[5];
    const void*  flat_netpin  = d_in[6];
    float* out = (float*)d_out;

    int num_pins    = in_sizes[1] / 2;
    int num_nodes   = in_sizes[2];
    int num_nets    = in_sizes[4];
    int num_movable = out_size;

    size_t grid_f = (size_t)NB * NB * 2;              // one chunk (h+v)
    size_t P_f    = (size_t)NCHUNK * grid_f;          // 16 MB
    size_t need   = (P_f + (size_t)NB * NB) * sizeof(float);

    if (ws_size >= need) {
        float* P  = (float*)d_ws;
        float* ut = P + P_f;
        accum_fused<<<NWIN * NCHUNK, K1_THREADS, 0, stream>>>(
            pin_pos, net_weights, netpin_start, flat_netpin, P,
            num_nets, num_pins);
        colscan_util<<<NB, 512, 0, stream>>>(P, ut);
        int gi = (num_movable + 255) / 256;
        instance_area<<<gi, 256, 0, stream>>>(pos, nsx, nsy, ut, out,
                                              num_movable, num_nodes);
        return;
    }

    // -------- fallback: round-1 style (768KB workspace) --------
    {
        float* G2   = (float*)d_ws;
        float* util = G2 + NB * NB * 2;    // utilT [x][y]
        fb_zero<<<256, 256, 0, stream>>>(G2, NB * NB * 2);
        int gn = (num_nets + 255) / 256;
        fb_scatter<<<gn, 256, 0, stream>>>(pin_pos, net_weights, netpin_start,
                                           flat_netpin, G2, num_nets, num_pins);
        fb_rowscan<<<NB, 256, 0, stream>>>((float2*)G2);
        fb_colscan<<<NB, 256, 0, stream>>>((const float2*)G2, util);
        int gi = (num_movable + 255) / 256;
        instance_area<<<gi, 256, 0, stream>>>(pos, nsx, nsy, util, out,
                                              num_movable, num_nodes);
    }
}